// Round 5
// baseline (110.454 us; speedup 1.0000x reference)
//
#include <hip/hip_runtime.h>
#include <hip/hip_cooperative_groups.h>

namespace cg = cooperative_groups;

#define SCALE 0.35355339059327379f   // 8^-0.5
#define RSQRT2 0.70710678118654752f

// ws layout (float offsets)
#define QT_SZ   (68*68*64)           // padded transposed q image: [xp][yp][ic]
#define WT_SZ   (64*64*132)          // [oc][ic][kh][12]
#define QT_OFF  0
#define KT_OFF  (QT_OFF + QT_SZ)
#define WQT_OFF (KT_OFF + QT_SZ)
#define WKT_OFF (WQT_OFF + WT_SZ)
#define QD_OFF  (WKT_OFF + WT_SZ)    // [oc][il] 64*64
#define KD_OFF  (QD_OFF + 4096)
#define VP_OFF  (KD_OFF + 4096)      // Vpart [yg][x][ch] 8*64*64
#define VR_OFF  (VP_OFF + 8*64*64)   // Vrow  [jl][ch] 64*64

__global__ __launch_bounds__(512) void fused(const float* __restrict__ f,
                                             const float* __restrict__ w_qkv,
                                             const float* __restrict__ wq,
                                             const float* __restrict__ wk,
                                             const float* __restrict__ bq,
                                             const float* __restrict__ bk,
                                             float* __restrict__ ws,
                                             float* __restrict__ out)
{
    __shared__ float smem[14080];   // 56.3 KB: P1 wt+fl (13888) / P2 patch 64x220 (14080) / P3 vrow (4160)
    const int b = blockIdx.x, t = threadIdx.x;
    cg::grid_group grid = cg::this_grid();

    // ================= P1: 1x1 qkv conv + weight transpose =================
    {
        float* wt = smem;            // [64 ic][193] transposed w_qkv
        float* fl = smem + 12352;    // [2 tasks][64 ic][12]
        if (t < 384) {
            const int sub = (t >= 192) ? 1 : 0;
            const int tt  = t - sub*192;
            #pragma unroll
            for (int j = 0; j < 8; ++j) {
                const int idx = t + 384*j;          // float4 idx in [0,3072)
                float4 v = *(const float4*)(w_qkv + 4*idx);
                const int oc = idx >> 4, ic0 = (4*idx) & 63;
                wt[(ic0+0)*193 + oc] = v.x;
                wt[(ic0+1)*193 + oc] = v.y;
                wt[(ic0+2)*193 + oc] = v.z;
                wt[(ic0+3)*193 + oc] = v.w;
            }
            if (tt < 128) {
                const int tid = b*2 + sub;
                const int x = tid >> 3, yg = tid & 7;
                const int ic = tt >> 1, part = tt & 1;
                *(float4*)&fl[sub*768 + ic*12 + part*4] =
                    *(const float4*)(f + ic*4096 + x*64 + yg*8 + part*4);
            }
        } else {
            // wq/wk [oc][ic][11][11] -> [oc][ic][kh][12]; task = b>>1, half = b&1
            const int task = b >> 1, half = b & 1;
            const int type = task >> 6, oc = task & 63;
            const float* wsrc = (type ? wk : wq) + oc*7744;
            float* wdst = (ws + (type ? WKT_OFF : WQT_OFF)) + oc*64*132;
            for (int p = half*352 + (t - 384); p < half*352 + 352; p += 128) {
                const int ic = p / 11, kh = p % 11;
                const float* s = wsrc + ic*121 + kh*11;
                float* d = wdst + ic*132 + kh*12;
                #pragma unroll
                for (int kw = 0; kw < 11; ++kw) d[kw] = s[kw];
            }
        }
        __syncthreads();
        if (t < 384) {
            const int sub = (t >= 192) ? 1 : 0;
            const int tt  = t - sub*192;
            const int w = tt >> 6, lane = tt & 63;
            const int tid = b*2 + sub;
            const int x = tid >> 3, yg = tid & 7;
            const float* flp = &fl[sub*768];
            float acc[8] = {0.f,0.f,0.f,0.f,0.f,0.f,0.f,0.f};
            #pragma unroll 8
            for (int ic = 0; ic < 64; ++ic) {
                const float wv = wt[ic*193 + w*64 + lane];
                const float4 a = *(const float4*)&flp[ic*12];
                const float4 c = *(const float4*)&flp[ic*12 + 4];
                acc[0] = fmaf(wv,a.x,acc[0]); acc[1] = fmaf(wv,a.y,acc[1]);
                acc[2] = fmaf(wv,a.z,acc[2]); acc[3] = fmaf(wv,a.w,acc[3]);
                acc[4] = fmaf(wv,c.x,acc[4]); acc[5] = fmaf(wv,c.y,acc[5]);
                acc[6] = fmaf(wv,c.z,acc[6]); acc[7] = fmaf(wv,c.w,acc[7]);
            }
            if (w < 2) {
                float* img = ws + (w == 0 ? QT_OFF : KT_OFF);
                const int rowb = (x + 2) * 68;
                #pragma unroll
                for (int j = 0; j < 8; ++j)
                    img[(rowb + yg*8 + j + 2)*64 + lane] = acc[j];
                if (yg == 0) { img[(rowb+0)*64+lane] = 0.f; img[(rowb+1)*64+lane] = 0.f; }
                if (yg == 7) { img[(rowb+66)*64+lane] = 0.f; img[(rowb+67)*64+lane] = 0.f; }
                if (x < 4) {
                    const int xp = (x < 2) ? x : 64 + x;
                    for (int yp = yg*9; yp < yg*9 + 9; ++yp)
                        if (yp < 68) img[(xp*68 + yp)*64 + lane] = 0.f;
                }
            } else {
                const float s = acc[0]+acc[1]+acc[2]+acc[3]+acc[4]+acc[5]+acc[6]+acc[7];
                (ws + VP_OFF)[(yg*64 + x)*64 + lane] = s * 0.015625f;
            }
        }
    }
    grid.sync();

    // ================= P2: 11x11 s8 conv + GELU (all 256 blocks) =================
    {
        const int type = b >> 7, ox = (b >> 4) & 7, ocg = (b >> 1) & 7, oyh = b & 1;
        const float* img  = ws + (type ? KT_OFF : QT_OFF);
        const float* wT   = ws + (type ? WKT_OFF : WQT_OFF);
        const float* bias = type ? bk : bq;
        float* outp = ws + (type ? KD_OFF : QD_OFF);
        const int ocp = t >> 6, lane = t & 63;      // wave = 1 oc, lane = ic
        const int oc = ocg*8 + ocp;
        const float* wb = wT + (oc*64 + lane)*132;
        float acc0 = 0.f, acc1 = 0.f, acc2 = 0.f, acc3 = 0.f;
        float* prow_base = smem + lane*220;          // pitch 220: 16B-aligned, odd float4-stride

#define CONV_CHUNK(KH0, NKH, FIRST)                                              \
        {                                                                        \
            if (!(FIRST)) __syncthreads();                                       \
            for (int kh = 0; kh < (NKH); ++kh) {                                 \
                const int xrow = (ox*8 + (KH0) + kh) * 68;                       \
                for (int yl = ocp; yl < 35; yl += 8)                             \
                    prow_base[kh*36 + yl] = img[(xrow + oyh*32 + yl)*64 + lane]; \
            }                                                                    \
            __syncthreads();                                                     \
            _Pragma("unroll")                                                    \
            for (int kh = 0; kh < (NKH); ++kh) {                                 \
                const float4* p4 = (const float4*)(prow_base + kh*36);           \
                float pr[36];                                                    \
                _Pragma("unroll")                                                \
                for (int q = 0; q < 9; ++q) {                                    \
                    const float4 v = p4[q];                                      \
                    pr[4*q] = v.x; pr[4*q+1] = v.y; pr[4*q+2] = v.z; pr[4*q+3] = v.w; \
                }                                                                \
                const int khg = (KH0) + kh;                                      \
                const float4 wa = *(const float4*)(wb + khg*12);                 \
                const float4 wm = *(const float4*)(wb + khg*12 + 4);             \
                const float4 wc = *(const float4*)(wb + khg*12 + 8);             \
                const float wgt[11] = {wa.x,wa.y,wa.z,wa.w,                      \
                                       wm.x,wm.y,wm.z,wm.w, wc.x,wc.y,wc.z};     \
                _Pragma("unroll")                                                \
                for (int kw = 0; kw < 11; ++kw) {                                \
                    acc0 = fmaf(wgt[kw], pr[kw],      acc0);                     \
                    acc1 = fmaf(wgt[kw], pr[kw + 8],  acc1);                     \
                    acc2 = fmaf(wgt[kw], pr[kw + 16], acc2);                     \
                    acc3 = fmaf(wgt[kw], pr[kw + 24], acc3);                     \
                }                                                                \
            }                                                                    \
        }
        CONV_CHUNK(0, 6, 1)
        CONV_CHUNK(6, 5, 0)
#undef CONV_CHUNK

        #pragma unroll
        for (int m = 1; m < 64; m <<= 1) {
            acc0 += __shfl_xor(acc0, m, 64);
            acc1 += __shfl_xor(acc1, m, 64);
            acc2 += __shfl_xor(acc2, m, 64);
            acc3 += __shfl_xor(acc3, m, 64);
        }
        if (lane == 0) {
            const float bb = bias[oc];
            const float v[4] = {acc0+bb, acc1+bb, acc2+bb, acc3+bb};
            #pragma unroll
            for (int j = 0; j < 4; ++j) {
                const int il = ox*8 + oyh*4 + j;
                outp[oc*64 + il] = 0.5f*v[j]*(1.0f + erff(v[j]*RSQRT2));
            }
        }
        // Vrow reduce (blocks 0..63, one jl column each)
        if (b < 64 && t < 64) {
            float s = 0.f;
            #pragma unroll
            for (int yg = 0; yg < 8; ++yg)
                s += (ws + VP_OFF)[(yg*64 + b)*64 + t];
            (ws + VR_OFF)[b*64 + t] = s;     // [jl][ch]
        }
    }
    grid.sync();

    // ================= P3: dots + softmax + PV (blocks 0..63) =================
    if (b < 64) {
        float* vrow = smem;                   // [ch][jl] pitch 65
        const float* VrowG = ws + VR_OFF;
        for (int idx = t; idx < 4096; idx += 512) {
            const int jl = idx >> 6, ch = idx & 63;
            vrow[ch*65 + jl] = VrowG[idx];
        }
        __syncthreads();
        const int h = t >> 6, lane = t & 63;  // 8 waves = 8 heads
        const float* qd = ws + QD_OFF;
        const float* kd = ws + KD_OFF;
        float d = 0.f;
        #pragma unroll
        for (int c = 0; c < 8; ++c)
            d = fmaf(qd[(h*8 + c)*64 + b], kd[(h*8 + c)*64 + lane], d);
        d *= SCALE;
        float m = d;
        #pragma unroll
        for (int mm = 1; mm < 64; mm <<= 1) m = fmaxf(m, __shfl_xor(m, mm, 64));
        const float e = __expf(d - m);
        float ssum = e;
        #pragma unroll
        for (int mm = 1; mm < 64; mm <<= 1) ssum += __shfl_xor(ssum, mm, 64);
        const float p = e / ssum;
        #pragma unroll
        for (int c = 0; c < 8; ++c) {
            float r = p * vrow[(h*8 + c)*65 + lane];
            #pragma unroll
            for (int mm = 1; mm < 64; mm <<= 1) r += __shfl_xor(r, mm, 64);
            out[(h*8 + c)*4096 + b*64 + lane] = r;
        }
    }
}

extern "C" void kernel_launch(void* const* d_in, const int* in_sizes, int n_in,
                              void* d_out, int out_size, void* d_ws, size_t ws_size,
                              hipStream_t stream) {
    const float* f     = (const float*)d_in[0];
    const float* w_qkv = (const float*)d_in[1];
    const float* wq    = (const float*)d_in[2];
    const float* bq    = (const float*)d_in[3];
    const float* wk    = (const float*)d_in[4];
    const float* bk    = (const float*)d_in[5];
    float* outp = (float*)d_out;
    float* wsp  = (float*)d_ws;

    void* args[] = { (void*)&f, (void*)&w_qkv, (void*)&wq, (void*)&wk,
                     (void*)&bq, (void*)&bk, (void*)&wsp, (void*)&outp };
    hipLaunchCooperativeKernel((void*)fused, dim3(256), dim3(512), args, 0, stream);
}